// Round 6
// baseline (729.087 us; speedup 1.0000x reference)
//
#include <hip/hip_runtime.h>
#include <hip/hip_bf16.h>

#define LEAK 0.2f
#define SENT 0x5CA1AB1Eu

typedef __attribute__((ext_vector_type(8))) short short8;
typedef __attribute__((ext_vector_type(4))) float f32x4;

// ---------- grid-wide software barrier (sentinel flags; poison-proof) ----------
// Requires all 512 blocks co-resident: grid=512, 2 blocks/CU by construction
// (LDS 30KB x2 <= 160KB, launch_bounds(256,2) caps VGPR <= 256 -> 8 waves/CU).
__device__ __forceinline__ void gridbar(unsigned* flags, int bar) {
  __syncthreads();
  __threadfence();  // release: make prior writes agent-visible
  if (threadIdx.x == 0)
    __hip_atomic_store(&flags[bar * 512 + blockIdx.x], SENT, __ATOMIC_RELEASE,
                       __HIP_MEMORY_SCOPE_AGENT);
  unsigned* base = &flags[bar * 512];
#pragma unroll
  for (int r = 0; r < 2; ++r) {
    int b = threadIdx.x + r * 256;
    while (__hip_atomic_load(&base[b], __ATOMIC_RELAXED, __HIP_MEMORY_SCOPE_AGENT) != SENT) {}
  }
  __threadfence();  // acquire: invalidate stale cache lines
  __syncthreads();
}

// ---------- phase 0: x->bf16 convert ++ W1,W2,T transpose+convert ----------
__device__ void prep_dev(int vb, int t, char* smem,
                         const float* __restrict__ x, __hip_bfloat16* __restrict__ xb,
                         const float* __restrict__ W1, __hip_bfloat16* __restrict__ W1t,
                         const float* __restrict__ W2, __hip_bfloat16* __restrict__ W2t,
                         const float* __restrict__ T, __hip_bfloat16* __restrict__ Tt) {
  if (vb < 6144) {
    int idx = vb * 256 + t;
    float4 v = reinterpret_cast<const float4*>(x)[idx];
    union { ushort4 u; __hip_bfloat16 h[4]; } c;
    c.h[0] = __float2bfloat16(v.x);
    c.h[1] = __float2bfloat16(v.y);
    c.h[2] = __float2bfloat16(v.z);
    c.h[3] = __float2bfloat16(v.w);
    reinterpret_cast<ushort4*>(xb)[idx] = c.u;
    return;
  }
  float (*tile)[33] = (float(*)[33])smem;
  const float* W;
  __hip_bfloat16* Wt;
  int K, N, kblk, nblk;
  int b2 = vb - 6144;
  if (b2 < 1536) {            // W1: 3072x512 -> 512x3072
    W = W1; Wt = W1t; K = 3072; N = 512;
    kblk = b2 % 96; nblk = b2 / 96;
  } else if (b2 < 1664) {     // W2: 512x256 -> 256x512
    int b3 = b2 - 1536;
    W = W2; Wt = W2t; K = 512; N = 256;
    kblk = b3 % 16; nblk = b3 / 16;
  } else {                    // T: 256x100 -> 128x256 (zero-pad)
    int b4 = b2 - 1664;
    W = T; Wt = Tt; K = 256; N = 100;
    kblk = b4 % 8; nblk = b4 / 8;
  }
  int k0 = kblk * 32, n0 = nblk * 32;
  int tx = t & 31, ty = t >> 5;
  __syncthreads();
#pragma unroll
  for (int r = 0; r < 4; ++r) {
    int n = n0 + tx;
    tile[ty + r * 8][tx] = (n < N) ? W[(long)(k0 + ty + r * 8) * N + n] : 0.f;
  }
  __syncthreads();
#pragma unroll
  for (int r = 0; r < 4; ++r)
    Wt[(long)(n0 + ty + r * 8) * K + k0 + tx] = __float2bfloat16(tile[tx][ty + r * 8]);
}

// ---------- bf16 MFMA GEMM tile (64x64, BK=64), r5-validated structure ----------
__device__ void gemm_dev(char* smem, const __hip_bfloat16* __restrict__ A,
                         const __hip_bfloat16* __restrict__ Bt, float* __restrict__ Cz,
                         int K, int kStart, int KSPL, int mt, int nt,
                         bool transp, int ldO) {
  __hip_bfloat16 (*As)[72] = (__hip_bfloat16(*)[72])smem;
  __hip_bfloat16 (*Bs)[72] = (__hip_bfloat16(*)[72])(smem + 9216);
  int tid = threadIdx.x;
  int lane = tid & 63;
  int wv = tid >> 6;
  int wm = wv & 1, wn = wv >> 1;
  int quad = lane >> 4, l16 = lane & 15;
  long m0 = (long)mt * 64, n0 = (long)nt * 64;
  int srow = tid >> 2, scol = (tid & 3) * 16;
  const __hip_bfloat16* Ag = A + (m0 + srow) * K + kStart + scol;
  const __hip_bfloat16* Bg = Bt + (n0 + srow) * K + kStart + scol;

  int4 ra0 = *reinterpret_cast<const int4*>(Ag);
  int4 ra1 = *reinterpret_cast<const int4*>(Ag + 8);
  int4 rb0 = *reinterpret_cast<const int4*>(Bg);
  int4 rb1 = *reinterpret_cast<const int4*>(Bg + 8);

  f32x4 acc[2][2] = {};
  for (int kb = 0; kb < KSPL; kb += 64) {
    __syncthreads();  // protect smem union reuse across phases/iters
    *reinterpret_cast<int4*>(&As[srow][scol]) = ra0;
    *reinterpret_cast<int4*>(&As[srow][scol + 8]) = ra1;
    *reinterpret_cast<int4*>(&Bs[srow][scol]) = rb0;
    *reinterpret_cast<int4*>(&Bs[srow][scol + 8]) = rb1;
    __syncthreads();
    if (kb + 64 < KSPL) {
      ra0 = *reinterpret_cast<const int4*>(Ag + kb + 64);
      ra1 = *reinterpret_cast<const int4*>(Ag + kb + 72);
      rb0 = *reinterpret_cast<const int4*>(Bg + kb + 64);
      rb1 = *reinterpret_cast<const int4*>(Bg + kb + 72);
    }
#pragma unroll
    for (int half = 0; half < 2; ++half) {
      short8 af[2], bfr[2];
#pragma unroll
      for (int u = 0; u < 2; ++u) {
        af[u]  = *reinterpret_cast<const short8*>(&As[wm * 32 + u * 16 + l16][half * 32 + quad * 8]);
        bfr[u] = *reinterpret_cast<const short8*>(&Bs[wn * 32 + u * 16 + l16][half * 32 + quad * 8]);
      }
#pragma unroll
      for (int tm = 0; tm < 2; ++tm)
#pragma unroll
        for (int tn = 0; tn < 2; ++tn)
          acc[tm][tn] =
              __builtin_amdgcn_mfma_f32_16x16x32_bf16(af[tm], bfr[tn], acc[tm][tn], 0, 0, 0);
    }
  }
#pragma unroll
  for (int tm = 0; tm < 2; ++tm)
#pragma unroll
    for (int tn = 0; tn < 2; ++tn)
#pragma unroll
      for (int r = 0; r < 4; ++r) {
        long gm = m0 + wm * 32 + tm * 16 + quad * 4 + r;  // row = quad*4 + reg
        long gn = n0 + wn * 32 + tn * 16 + l16;           // col = lane&15
        if (transp) Cz[gn * (long)ldO + gm] = acc[tm][tn][r];
        else        Cz[gm * (long)ldO + gn] = acc[tm][tn][r];
      }
}

// ---------- combine NZ partials + bias + leakyrelu -> bf16 (+ optional fp32) ----------
__device__ void comb_dev(int vb, int t, const float* __restrict__ P,
                         const float* __restrict__ bias, float* __restrict__ Of,
                         __hip_bfloat16* __restrict__ Ob, int total4, int nmask, int nz,
                         bool outf) {
  int idx = vb * 256 + t;
  float4 v = reinterpret_cast<const float4*>(P)[idx];
  for (int z = 1; z < nz; ++z) {
    float4 a = reinterpret_cast<const float4*>(P + (long)z * total4 * 4)[idx];
    v.x += a.x; v.y += a.y; v.z += a.z; v.w += a.w;
  }
  int col = (idx * 4) & nmask;
  float4 bs = *reinterpret_cast<const float4*>(bias + col);
  v.x += bs.x; v.y += bs.y; v.z += bs.z; v.w += bs.w;
  v.x = v.x > 0.f ? v.x : LEAK * v.x;
  v.y = v.y > 0.f ? v.y : LEAK * v.y;
  v.z = v.z > 0.f ? v.z : LEAK * v.z;
  v.w = v.w > 0.f ? v.w : LEAK * v.w;
  if (outf) reinterpret_cast<float4*>(Of)[idx] = v;
  union { ushort4 u; __hip_bfloat16 h[4]; } c;
  c.h[0] = __float2bfloat16(v.x);
  c.h[1] = __float2bfloat16(v.y);
  c.h[2] = __float2bfloat16(v.z);
  c.h[3] = __float2bfloat16(v.w);
  reinterpret_cast<ushort4*>(Ob)[idx] = c.u;
}

// ---------- bucketed minibatch-discrimination features, O(B), 256 threads ----------
__device__ void bucket_dev(int f, int t, char* smem, const float* __restrict__ P4,
                           float* __restrict__ featsT) {
  float* sP = (float*)smem;                             // [0, 8192)
  float* sN = (float*)(smem + 8192);                    // [8192, 16384)
  unsigned short* perm = (unsigned short*)(smem + 16384);  // 4096
  unsigned char* sB = (unsigned char*)(smem + 20480);   // 2048
  int* cnt = (int*)(smem + 22528);
  int* bstart = (int*)(smem + 23552);
  int* bcur = (int*)(smem + 24576);
  float* bsP = (float*)(smem + 25600);
  float* bsN = (float*)(smem + 26624);
  float* Pbel = (float*)(smem + 27648);
  float* Nab = (float*)(smem + 28672);
  float* wred = (float*)(smem + 29696);                 // 8
  float* sMM = (float*)(smem + 29728);                  // 2
  int lane = t & 63, wv = t >> 6;
  const long FS = 2048L * 128;
  const float* row = P4 + (long)f * 2048;

  float m[8];
  float lmin = 3.4e38f, lmax = -3.4e38f;
#pragma unroll
  for (int r = 0; r < 8; ++r) {
    int e = t + r * 256;
    float v = row[e] + row[FS + e] + row[2 * FS + e] + row[3 * FS + e];
    m[r] = v;
    lmin = fminf(lmin, v);
    lmax = fmaxf(lmax, v);
  }
#pragma unroll
  for (int d = 32; d; d >>= 1) {
    lmin = fminf(lmin, __shfl_down(lmin, d));
    lmax = fmaxf(lmax, __shfl_down(lmax, d));
  }
  if (lane == 0) { wred[wv] = lmin; wred[4 + wv] = lmax; }
  cnt[t] = 0;
  __syncthreads();
  if (t == 0) {
    float a = wred[0], b = wred[4];
    for (int i = 1; i < 4; ++i) { a = fminf(a, wred[i]); b = fmaxf(b, wred[4 + i]); }
    sMM[0] = a; sMM[1] = b;
  }
  __syncthreads();
  float mn = sMM[0], mx = sMM[1];
  float rge = mx - mn;
  float scale = (rge > 1e-20f) ? 255.0f / rge : 0.f;
  float mid = 0.5f * (mn + mx);
#pragma unroll
  for (int r = 0; r < 8; ++r) {
    int e = t + r * 256;
    float v = m[r];
    int b = (int)((v - mn) * scale);
    b = b < 255 ? b : 255;
    float arg = fminf(fmaxf(v - mid, -60.f), 60.f);
    sP[e] = __expf(arg);
    sN[e] = __expf(-arg);
    sB[e] = (unsigned char)b;
    atomicAdd(&cnt[b], 1);
  }
  __syncthreads();
  if (wv == 0) {  // exclusive prefix of cnt (4 bins/lane + wave scan)
    int b4 = lane * 4;
    int c0 = cnt[b4], c1 = cnt[b4 + 1], c2 = cnt[b4 + 2], c3 = cnt[b4 + 3];
    int tot = c0 + c1 + c2 + c3;
    int inc = tot;
#pragma unroll
    for (int d = 1; d < 64; d <<= 1) {
      int y = __shfl_up(inc, d);
      if (lane >= d) inc += y;
    }
    int run = inc - tot;
    bstart[b4] = run; bcur[b4] = run; run += c0;
    bstart[b4 + 1] = run; bcur[b4 + 1] = run; run += c1;
    bstart[b4 + 2] = run; bcur[b4 + 2] = run; run += c2;
    bstart[b4 + 3] = run; bcur[b4 + 3] = run;
  }
  __syncthreads();
#pragma unroll
  for (int r = 0; r < 8; ++r) {  // scatter: bucket-ordered permutation
    int e = t + r * 256;
    int slot = atomicAdd(&bcur[sB[e]], 1);
    perm[slot] = (unsigned short)e;
  }
  __syncthreads();
  {  // per-bucket sums via perm indirection
    int s0 = bstart[t], s1 = s0 + cnt[t];
    float ap = 0.f, an = 0.f;
    for (int q = s0; q < s1; ++q) { int j = perm[q]; ap += sP[j]; an += sN[j]; }
    bsP[t] = ap; bsN[t] = an;
  }
  __syncthreads();
  if (wv == 0) {  // bucket-level exclusive prefix(P) / suffix(N)
    int b4 = lane * 4;
    float p0 = bsP[b4], p1 = bsP[b4 + 1], p2 = bsP[b4 + 2], p3 = bsP[b4 + 3];
    float n0 = bsN[b4], n1 = bsN[b4 + 1], n2 = bsN[b4 + 2], n3 = bsN[b4 + 3];
    float tp = p0 + p1 + p2 + p3, tn = n0 + n1 + n2 + n3;
    float ip = tp, in_ = tn;
#pragma unroll
    for (int d = 1; d < 64; d <<= 1) {
      float yp = __shfl_up(ip, d);
      float yn = __shfl_up(in_, d);
      if (lane >= d) { ip += yp; in_ += yn; }
    }
    float totn = __shfl(in_, 63);
    float runp = ip - tp;
    float runn = in_ - tn;
    Pbel[b4] = runp; Nab[b4] = totn - runn - n0; runp += p0; runn += n0;
    Pbel[b4 + 1] = runp; Nab[b4 + 1] = totn - runn - n1; runp += p1; runn += n1;
    Pbel[b4 + 2] = runp; Nab[b4 + 2] = totn - runn - n2; runp += p2; runn += n2;
    Pbel[b4 + 3] = runp; Nab[b4 + 3] = totn - runn - n3;
  }
  __syncthreads();
#pragma unroll
  for (int r = 0; r < 8; ++r) {
    int s = t + r * 256;
    int e = perm[s];
    int b = sB[e];
    float p = sP[e], n = sN[e];
    float acc = n * Pbel[b] + p * Nab[b];
    int q0 = bstart[b], q1 = q0 + cnt[b];
    for (int q = q0; q < q1; ++q) { int j = perm[q]; acc += fminf(p * sN[j], n * sP[j]); }
    featsT[(long)f * 2048 + e] = acc;
  }
}

// ---------- final dot ----------
__device__ void final_dev(int vb, int t, const float* __restrict__ h2f,
                          const float* __restrict__ featsT, const float* __restrict__ Wf,
                          const float* __restrict__ bfp, float* __restrict__ out) {
  int wv = t >> 6, lane = t & 63;
  long i = (long)vb * 4 + wv;
  const float* hrow = h2f + i * 256;
  float s = 0.f;
#pragma unroll
  for (int c = lane; c < 256; c += 64) s += hrow[c] * Wf[c];
  for (int f = lane; f < 100; f += 64) s += featsT[(long)f * 2048 + i] * Wf[256 + f];
#pragma unroll
  for (int off = 32; off; off >>= 1) s += __shfl_down(s, off);
  if (lane == 0) out[i] = s + bfp[0];
}

// ---------- the megakernel: all 8 phases, 7 grid barriers, 1 launch ----------
__global__ __launch_bounds__(256, 2) void k_mega(
    const float* x, const float* W1, const float* b1, const float* W2, const float* b2,
    const float* T, const float* Wf, const float* bf, float* out,
    __hip_bfloat16* xb, __hip_bfloat16* W1t, __hip_bfloat16* W2t, __hip_bfloat16* Tt,
    __hip_bfloat16* h1b, float* h2f, __hip_bfloat16* h2b, float* feT,
    float* P1, float* P2, float* P3, unsigned* flags) {
  __shared__ __align__(16) char smem[30720];
  int blk = blockIdx.x, t = threadIdx.x;

  // P0: prep (7840 vblocks)
  for (int vb = blk; vb < 7840; vb += 512)
    prep_dev(vb, t, smem, x, xb, W1, W1t, W2, W2t, T, Tt);
  gridbar(flags, 0);
  // P1: G1 = x @ W1 (64x64 tiles, 32x8, split-K=2, KSPL=1536)
  {
    int mt = blk & 31, nt = (blk >> 5) & 7, z = blk >> 8;
    gemm_dev(smem, xb, W1t, P1 + (long)z * 2048 * 512, 3072, z * 1536, 1536, mt, nt, false, 512);
  }
  gridbar(flags, 1);
  // P2: comb1 (1024 vblocks, NZ=2) -> h1b
  for (int vb = blk; vb < 1024; vb += 512)
    comb_dev(vb, t, P1, b1, nullptr, h1b, 262144, 511, 2, false);
  gridbar(flags, 2);
  // P3: G2 = h1 @ W2 (32x4 tiles, split-K=4, KSPL=128)
  {
    int mt = blk & 31, nt = (blk >> 5) & 3, z = blk >> 7;
    gemm_dev(smem, h1b, W2t, P2 + (long)z * 2048 * 256, 512, z * 128, 128, mt, nt, false, 256);
  }
  gridbar(flags, 3);
  // P4: comb2 (512 vblocks, NZ=4) -> h2f + h2b
  comb_dev(blk, t, P2, b2, h2f, h2b, 131072, 255, 4, true);
  gridbar(flags, 4);
  // P5: G3 = h2 @ T (32x2 tiles, split-K=4, KSPL=64, transposed store)
  if (blk < 256) {
    int mt = blk & 31, nt = (blk >> 5) & 1, z = blk >> 6;
    gemm_dev(smem, h2b, Tt, P3 + (long)z * 2048 * 128, 256, z * 64, 64, mt, nt, true, 2048);
  }
  gridbar(flags, 5);
  // P6: bucketed features (100 vblocks)
  if (blk < 100) bucket_dev(blk, t, smem, P3, feT);
  gridbar(flags, 6);
  // P7: final dot (512 vblocks)
  final_dev(blk, t, h2f, feT, Wf, bf, out);
}

extern "C" void kernel_launch(void* const* d_in, const int* in_sizes, int n_in,
                              void* d_out, int out_size, void* d_ws, size_t ws_size,
                              hipStream_t stream) {
  const float* x  = (const float*)d_in[0];
  const float* W1 = (const float*)d_in[1];
  const float* b1 = (const float*)d_in[2];
  const float* W2 = (const float*)d_in[3];
  const float* b2 = (const float*)d_in[4];
  const float* T  = (const float*)d_in[5];
  const float* Wf = (const float*)d_in[6];
  const float* bf = (const float*)d_in[7];
  float* out = (float*)d_out;

  char* w = (char*)d_ws;
  auto alloc = [&](size_t b) { char* p = w; w += (b + 255) & ~(size_t)255; return p; };
  __hip_bfloat16* xb  = (__hip_bfloat16*)alloc(2048L * 3072 * 2);  // 12 MB
  __hip_bfloat16* W1t = (__hip_bfloat16*)alloc(512L * 3072 * 2);   // 3 MB
  __hip_bfloat16* W2t = (__hip_bfloat16*)alloc(256L * 512 * 2);
  __hip_bfloat16* Tt  = (__hip_bfloat16*)alloc(128L * 256 * 2);
  __hip_bfloat16* h1b = (__hip_bfloat16*)alloc(2048L * 512 * 2);   // 2 MB
  float*          h2f = (float*)alloc(2048L * 256 * 4);            // 2 MB
  __hip_bfloat16* h2b = (__hip_bfloat16*)alloc(2048L * 256 * 2);   // 1 MB
  float*          feT = (float*)alloc(100L * 2048 * 4);            // 0.8 MB
  float*          P1  = (float*)alloc(2L * 2048 * 512 * 4);        // 8 MB
  float*          P2  = (float*)alloc(4L * 2048 * 256 * 4);        // 8 MB
  float*          P3  = (float*)alloc(4L * 2048 * 128 * 4);        // 4 MB
  unsigned*     flags = (unsigned*)alloc(7L * 512 * 4);            // 14 KB

  k_mega<<<512, 256, 0, stream>>>(x, W1, b1, W2, b2, T, Wf, bf, out,
                                  xb, W1t, W2t, Tt, h1b, h2f, h2b, feT,
                                  P1, P2, P3, flags);
}

// Round 7
// 180.171 us; speedup vs baseline: 4.0466x; 4.0466x over previous
//
#include <hip/hip_runtime.h>
#include <hip/hip_bf16.h>

#define LEAK 0.2f

typedef __attribute__((ext_vector_type(8))) short short8;
typedef __attribute__((ext_vector_type(4))) float f32x4;

union bfpack { int4 i; __hip_bfloat16 h[8]; };

// ---------- prep: W1,W2,T transpose+convert (1696 blocks) ----------
__global__ __launch_bounds__(256) void k_prep(const float* __restrict__ W1,
                                              __hip_bfloat16* __restrict__ W1t,
                                              const float* __restrict__ W2,
                                              __hip_bfloat16* __restrict__ W2t,
                                              const float* __restrict__ T,
                                              __hip_bfloat16* __restrict__ Tt) {
  __shared__ float tile[32][33];
  int b = blockIdx.x, t = threadIdx.x;
  const float* W;
  __hip_bfloat16* Wt;
  int K, N, kblk, nblk;
  if (b < 1536) {            // W1: 3072x512 -> 512x3072
    W = W1; Wt = W1t; K = 3072; N = 512;
    kblk = b % 96; nblk = b / 96;
  } else if (b < 1664) {     // W2: 512x256 -> 256x512
    int b3 = b - 1536;
    W = W2; Wt = W2t; K = 512; N = 256;
    kblk = b3 % 16; nblk = b3 / 16;
  } else {                   // T: 256x100 -> 128x256 (zero-pad)
    int b4 = b - 1664;
    W = T; Wt = Tt; K = 256; N = 100;
    kblk = b4 % 8; nblk = b4 / 8;
  }
  int k0 = kblk * 32, n0 = nblk * 32;
  int tx = t & 31, ty = t >> 5;
#pragma unroll
  for (int r = 0; r < 4; ++r) {
    int n = n0 + tx;
    tile[ty + r * 8][tx] = (n < N) ? W[(long)(k0 + ty + r * 8) * N + n] : 0.f;
  }
  __syncthreads();
#pragma unroll
  for (int r = 0; r < 4; ++r)
    Wt[(long)(n0 + ty + r * 8) * K + k0 + tx] = __float2bfloat16(tile[tx][ty + r * 8]);
}

// ---------- G1: P1[z] = x(fp32, convert-on-stage) @ W1t^T, split-K=3, BK=64 ----------
__global__ __launch_bounds__(256) void k_gemm1(const float* __restrict__ A,
                                               const __hip_bfloat16* __restrict__ Bt,
                                               float* __restrict__ Cp) {
  const int K = 3072, N = 512, KSPL = 1024;
  __shared__ __align__(16) __hip_bfloat16 As[64][72];
  __shared__ __align__(16) __hip_bfloat16 Bs[64][72];
  int tid = threadIdx.x, lane = tid & 63, wv = tid >> 6;
  int wm = wv & 1, wn = wv >> 1, quad = lane >> 4, l16 = lane & 15;
  long m0 = (long)blockIdx.x * 64, n0 = (long)blockIdx.y * 64;
  int kStart = blockIdx.z * KSPL;
  int srow = tid >> 2, scol = (tid & 3) * 16;
  const float* Ag = A + (m0 + srow) * K + kStart + scol;
  const __hip_bfloat16* Bg = Bt + (n0 + srow) * K + kStart + scol;

  auto loadA = [&](int kb, int4& o0, int4& o1) {
    float4 f0 = *reinterpret_cast<const float4*>(Ag + kb);
    float4 f1 = *reinterpret_cast<const float4*>(Ag + kb + 4);
    float4 f2 = *reinterpret_cast<const float4*>(Ag + kb + 8);
    float4 f3 = *reinterpret_cast<const float4*>(Ag + kb + 12);
    bfpack u0, u1;
    u0.h[0] = __float2bfloat16(f0.x); u0.h[1] = __float2bfloat16(f0.y);
    u0.h[2] = __float2bfloat16(f0.z); u0.h[3] = __float2bfloat16(f0.w);
    u0.h[4] = __float2bfloat16(f1.x); u0.h[5] = __float2bfloat16(f1.y);
    u0.h[6] = __float2bfloat16(f1.z); u0.h[7] = __float2bfloat16(f1.w);
    u1.h[0] = __float2bfloat16(f2.x); u1.h[1] = __float2bfloat16(f2.y);
    u1.h[2] = __float2bfloat16(f2.z); u1.h[3] = __float2bfloat16(f2.w);
    u1.h[4] = __float2bfloat16(f3.x); u1.h[5] = __float2bfloat16(f3.y);
    u1.h[6] = __float2bfloat16(f3.z); u1.h[7] = __float2bfloat16(f3.w);
    o0 = u0.i; o1 = u1.i;
  };

  int4 ra0, ra1, rb0, rb1;
  loadA(0, ra0, ra1);
  rb0 = *reinterpret_cast<const int4*>(Bg);
  rb1 = *reinterpret_cast<const int4*>(Bg + 8);

  f32x4 acc[2][2] = {};
  for (int kb = 0; kb < KSPL; kb += 64) {
    *reinterpret_cast<int4*>(&As[srow][scol]) = ra0;
    *reinterpret_cast<int4*>(&As[srow][scol + 8]) = ra1;
    *reinterpret_cast<int4*>(&Bs[srow][scol]) = rb0;
    *reinterpret_cast<int4*>(&Bs[srow][scol + 8]) = rb1;
    __syncthreads();
    if (kb + 64 < KSPL) {
      loadA(kb + 64, ra0, ra1);
      rb0 = *reinterpret_cast<const int4*>(Bg + kb + 64);
      rb1 = *reinterpret_cast<const int4*>(Bg + kb + 72);
    }
#pragma unroll
    for (int half = 0; half < 2; ++half) {
      short8 af[2], bfr[2];
#pragma unroll
      for (int u = 0; u < 2; ++u) {
        af[u]  = *reinterpret_cast<const short8*>(&As[wm * 32 + u * 16 + l16][half * 32 + quad * 8]);
        bfr[u] = *reinterpret_cast<const short8*>(&Bs[wn * 32 + u * 16 + l16][half * 32 + quad * 8]);
      }
#pragma unroll
      for (int tm = 0; tm < 2; ++tm)
#pragma unroll
        for (int tn = 0; tn < 2; ++tn)
          acc[tm][tn] =
              __builtin_amdgcn_mfma_f32_16x16x32_bf16(af[tm], bfr[tn], acc[tm][tn], 0, 0, 0);
    }
    __syncthreads();
  }

  float* Cz = Cp + (long)blockIdx.z * 2048 * 512;
#pragma unroll
  for (int tm = 0; tm < 2; ++tm)
#pragma unroll
    for (int tn = 0; tn < 2; ++tn)
#pragma unroll
      for (int r = 0; r < 4; ++r) {
        long gm = m0 + wm * 32 + tm * 16 + quad * 4 + r;
        long gn = n0 + wn * 32 + tn * 16 + l16;
        Cz[gm * N + gn] = acc[tm][tn][r];
      }
}

// ---------- G2: h2 = leaky(h1 @ W2t^T + b2); h1 built on-stage from 3 P1 partials ----------
__global__ __launch_bounds__(256) void k_gemm2(const float* __restrict__ P1,
                                               const float* __restrict__ b1,
                                               const __hip_bfloat16* __restrict__ Bt,
                                               const float* __restrict__ b2,
                                               __hip_bfloat16* __restrict__ h2b,
                                               float* __restrict__ h2f) {
  const int K = 512, N = 256;
  const long FS = 2048L * 512;
  __shared__ __align__(16) __hip_bfloat16 As[64][72];
  __shared__ __align__(16) __hip_bfloat16 Bs[64][72];
  int tid = threadIdx.x, lane = tid & 63, wv = tid >> 6;
  int wm = wv & 1, wn = wv >> 1, quad = lane >> 4, l16 = lane & 15;
  long m0 = (long)blockIdx.x * 64, n0 = (long)blockIdx.y * 64;
  int srow = tid >> 2, scol = (tid & 3) * 16;
  const float* Ag = P1 + (m0 + srow) * K + scol;
  const __hip_bfloat16* Bg = Bt + (n0 + srow) * K + scol;

  auto loadA = [&](int kb, int4& o0, int4& o1) {
    float4 v[4];
#pragma unroll
    for (int j = 0; j < 4; ++j) v[j] = *reinterpret_cast<const float4*>(Ag + kb + j * 4);
#pragma unroll
    for (int z = 1; z < 3; ++z)
#pragma unroll
      for (int j = 0; j < 4; ++j) {
        float4 a = *reinterpret_cast<const float4*>(Ag + z * FS + kb + j * 4);
        v[j].x += a.x; v[j].y += a.y; v[j].z += a.z; v[j].w += a.w;
      }
#pragma unroll
    for (int j = 0; j < 4; ++j) {
      float4 bs = *reinterpret_cast<const float4*>(b1 + kb + scol + j * 4);
      v[j].x += bs.x; v[j].y += bs.y; v[j].z += bs.z; v[j].w += bs.w;
      v[j].x = v[j].x > 0.f ? v[j].x : LEAK * v[j].x;
      v[j].y = v[j].y > 0.f ? v[j].y : LEAK * v[j].y;
      v[j].z = v[j].z > 0.f ? v[j].z : LEAK * v[j].z;
      v[j].w = v[j].w > 0.f ? v[j].w : LEAK * v[j].w;
    }
    bfpack u0, u1;
    u0.h[0] = __float2bfloat16(v[0].x); u0.h[1] = __float2bfloat16(v[0].y);
    u0.h[2] = __float2bfloat16(v[0].z); u0.h[3] = __float2bfloat16(v[0].w);
    u0.h[4] = __float2bfloat16(v[1].x); u0.h[5] = __float2bfloat16(v[1].y);
    u0.h[6] = __float2bfloat16(v[1].z); u0.h[7] = __float2bfloat16(v[1].w);
    u1.h[0] = __float2bfloat16(v[2].x); u1.h[1] = __float2bfloat16(v[2].y);
    u1.h[2] = __float2bfloat16(v[2].z); u1.h[3] = __float2bfloat16(v[2].w);
    u1.h[4] = __float2bfloat16(v[3].x); u1.h[5] = __float2bfloat16(v[3].y);
    u1.h[6] = __float2bfloat16(v[3].z); u1.h[7] = __float2bfloat16(v[3].w);
    o0 = u0.i; o1 = u1.i;
  };

  int4 ra0, ra1, rb0, rb1;
  loadA(0, ra0, ra1);
  rb0 = *reinterpret_cast<const int4*>(Bg);
  rb1 = *reinterpret_cast<const int4*>(Bg + 8);

  f32x4 acc[2][2] = {};
  for (int kb = 0; kb < K; kb += 64) {
    *reinterpret_cast<int4*>(&As[srow][scol]) = ra0;
    *reinterpret_cast<int4*>(&As[srow][scol + 8]) = ra1;
    *reinterpret_cast<int4*>(&Bs[srow][scol]) = rb0;
    *reinterpret_cast<int4*>(&Bs[srow][scol + 8]) = rb1;
    __syncthreads();
    if (kb + 64 < K) {
      loadA(kb + 64, ra0, ra1);
      rb0 = *reinterpret_cast<const int4*>(Bg + kb + 64);
      rb1 = *reinterpret_cast<const int4*>(Bg + kb + 72);
    }
#pragma unroll
    for (int half = 0; half < 2; ++half) {
      short8 af[2], bfr[2];
#pragma unroll
      for (int u = 0; u < 2; ++u) {
        af[u]  = *reinterpret_cast<const short8*>(&As[wm * 32 + u * 16 + l16][half * 32 + quad * 8]);
        bfr[u] = *reinterpret_cast<const short8*>(&Bs[wn * 32 + u * 16 + l16][half * 32 + quad * 8]);
      }
#pragma unroll
      for (int tm = 0; tm < 2; ++tm)
#pragma unroll
        for (int tn = 0; tn < 2; ++tn)
          acc[tm][tn] =
              __builtin_amdgcn_mfma_f32_16x16x32_bf16(af[tm], bfr[tn], acc[tm][tn], 0, 0, 0);
    }
    __syncthreads();
  }

#pragma unroll
  for (int tm = 0; tm < 2; ++tm)
#pragma unroll
    for (int tn = 0; tn < 2; ++tn)
#pragma unroll
      for (int r = 0; r < 4; ++r) {
        long gm = m0 + wm * 32 + tm * 16 + quad * 4 + r;
        long gn = n0 + wn * 32 + tn * 16 + l16;
        float v = acc[tm][tn][r] + b2[gn];
        v = v > 0.f ? v : LEAK * v;
        h2b[gm * N + gn] = __float2bfloat16(v);
        h2f[gm * N + gn] = v;
      }
}

// ---------- G3: P3[z] = (h2b @ Tt^T)^T, split-K=4; block(0,0,0) zeroes out[] ----------
__global__ __launch_bounds__(256) void k_gemm3(const __hip_bfloat16* __restrict__ A,
                                               const __hip_bfloat16* __restrict__ Bt,
                                               float* __restrict__ Cp,
                                               float* __restrict__ out) {
  const int K = 256;
  __shared__ __align__(16) __hip_bfloat16 As[64][72];
  __shared__ __align__(16) __hip_bfloat16 Bs[64][72];
  int tid = threadIdx.x;
  if (blockIdx.x == 0 && blockIdx.y == 0 && blockIdx.z == 0) {
#pragma unroll
    for (int r = 0; r < 8; ++r) out[tid + r * 256] = 0.f;  // zero before bucket launch
  }
  int lane = tid & 63, wv = tid >> 6;
  int wm = wv & 1, wn = wv >> 1, quad = lane >> 4, l16 = lane & 15;
  long m0 = (long)blockIdx.x * 64, n0 = (long)blockIdx.y * 64;
  int kStart = blockIdx.z * 64;
  int srow = tid >> 2, scol = (tid & 3) * 16;
  const __hip_bfloat16* Ag = A + (m0 + srow) * K + kStart + scol;
  const __hip_bfloat16* Bg = Bt + (n0 + srow) * K + kStart + scol;

  *reinterpret_cast<int4*>(&As[srow][scol]) = *reinterpret_cast<const int4*>(Ag);
  *reinterpret_cast<int4*>(&As[srow][scol + 8]) = *reinterpret_cast<const int4*>(Ag + 8);
  *reinterpret_cast<int4*>(&Bs[srow][scol]) = *reinterpret_cast<const int4*>(Bg);
  *reinterpret_cast<int4*>(&Bs[srow][scol + 8]) = *reinterpret_cast<const int4*>(Bg + 8);
  __syncthreads();
  f32x4 acc[2][2] = {};
#pragma unroll
  for (int half = 0; half < 2; ++half) {
    short8 af[2], bfr[2];
#pragma unroll
    for (int u = 0; u < 2; ++u) {
      af[u]  = *reinterpret_cast<const short8*>(&As[wm * 32 + u * 16 + l16][half * 32 + quad * 8]);
      bfr[u] = *reinterpret_cast<const short8*>(&Bs[wn * 32 + u * 16 + l16][half * 32 + quad * 8]);
    }
#pragma unroll
    for (int tm = 0; tm < 2; ++tm)
#pragma unroll
      for (int tn = 0; tn < 2; ++tn)
        acc[tm][tn] =
            __builtin_amdgcn_mfma_f32_16x16x32_bf16(af[tm], bfr[tn], acc[tm][tn], 0, 0, 0);
  }
  float* Cz = Cp + (long)blockIdx.z * 2048 * 128;
#pragma unroll
  for (int tm = 0; tm < 2; ++tm)
#pragma unroll
    for (int tn = 0; tn < 2; ++tn)
#pragma unroll
      for (int r = 0; r < 4; ++r) {
        long gm = m0 + wm * 32 + tm * 16 + quad * 4 + r;
        long gn = n0 + wn * 32 + tn * 16 + l16;
        Cz[gn * 2048 + gm] = acc[tm][tn][r];  // transposed partial: mTz[n][m]
      }
}

// ---------- bucketed features + fused final dot (atomicAdd into zeroed out[]) ----------
// blocks 0..99: feature f -> atomicAdd(out[i], feats_f[i]*Wf[256+f])
// blocks 100..101: base -> atomicAdd(out[i], h2f[i,:].Wf[0:256] + bf)
__global__ __launch_bounds__(1024) void k_bucketfinal(const float* __restrict__ mTz,
                                                      const float* __restrict__ h2f,
                                                      const float* __restrict__ Wf,
                                                      const float* __restrict__ bfp,
                                                      float* __restrict__ out) {
  __shared__ float sP[2048], sN[2048];
  __shared__ float Sp[2048], Sn[2048];
  __shared__ int Smeta[2048];
  __shared__ short sB[2048];
  __shared__ int cnt[256], bstart[256], bcur[256];
  __shared__ float bsP[256], bsN[256], Pbel[256], Nab[256];
  __shared__ float wred[32];
  __shared__ float sMin, sMax;
  int blk = blockIdx.x;
  int t = threadIdx.x;
  int lane = t & 63, wv = t >> 6;

  if (blk >= 100) {  // base dot: 2 blocks x 16 waves, 64 rows/wave
    int gw = (blk - 100) * 16 + wv;
    float bf0 = bfp[0];
    for (int rr = 0; rr < 64; ++rr) {
      long i = (long)gw * 64 + rr;
      const float* hrow = h2f + i * 256;
      float s = 0.f;
#pragma unroll
      for (int c = lane; c < 256; c += 64) s += hrow[c] * Wf[c];
#pragma unroll
      for (int off = 32; off; off >>= 1) s += __shfl_down(s, off);
      if (lane == 0) atomicAdd(&out[i], s + bf0);
    }
    return;
  }

  int f = blk;
  const long FS = 2048L * 128;
  const float* row = mTz + (long)f * 2048;
  float wff = Wf[256 + f];

  float m[2];
  float lmin = 3.4e38f, lmax = -3.4e38f;
#pragma unroll
  for (int r = 0; r < 2; ++r) {
    int e = t + r * 1024;
    float v = row[e] + row[FS + e] + row[2 * FS + e] + row[3 * FS + e];
    m[r] = v;
    lmin = fminf(lmin, v);
    lmax = fmaxf(lmax, v);
  }
#pragma unroll
  for (int d = 32; d; d >>= 1) {
    lmin = fminf(lmin, __shfl_down(lmin, d));
    lmax = fmaxf(lmax, __shfl_down(lmax, d));
  }
  if (lane == 0) { wred[wv] = lmin; wred[16 + wv] = lmax; }
  if (t < 256) cnt[t] = 0;
  __syncthreads();
  if (t == 0) {
    float a = wred[0], b = wred[16];
    for (int i = 1; i < 16; ++i) { a = fminf(a, wred[i]); b = fmaxf(b, wred[16 + i]); }
    sMin = a; sMax = b;
  }
  __syncthreads();
  float mn = sMin, mx = sMax;
  float rge = mx - mn;
  float scale = (rge > 1e-20f) ? 255.0f / rge : 0.f;
  float mid = 0.5f * (mn + mx);
#pragma unroll
  for (int r = 0; r < 2; ++r) {
    int e = t + r * 1024;
    float v = m[r];
    int b = (int)((v - mn) * scale);
    b = b < 255 ? b : 255;
    float arg = fminf(fmaxf(v - mid, -60.f), 60.f);
    sP[e] = __expf(arg);
    sN[e] = __expf(-arg);
    sB[e] = (short)b;
    atomicAdd(&cnt[b], 1);
  }
  __syncthreads();
  if (wv == 0) {  // exclusive prefix of cnt
    int b4 = lane * 4;
    int c0 = cnt[b4], c1 = cnt[b4 + 1], c2 = cnt[b4 + 2], c3 = cnt[b4 + 3];
    int tot = c0 + c1 + c2 + c3;
    int inc = tot;
#pragma unroll
    for (int d = 1; d < 64; d <<= 1) {
      int y = __shfl_up(inc, d);
      if (lane >= d) inc += y;
    }
    int run = inc - tot;
    bstart[b4] = run; bcur[b4] = run; run += c0;
    bstart[b4 + 1] = run; bcur[b4 + 1] = run; run += c1;
    bstart[b4 + 2] = run; bcur[b4 + 2] = run; run += c2;
    bstart[b4 + 3] = run; bcur[b4 + 3] = run;
  }
  __syncthreads();
#pragma unroll
  for (int r = 0; r < 2; ++r) {  // scatter into bucket order
    int e = t + r * 1024;
    int b = sB[e];
    int slot = atomicAdd(&bcur[b], 1);
    Sp[slot] = sP[e];
    Sn[slot] = sN[e];
    Smeta[slot] = (b << 16) | e;
  }
  __syncthreads();
  if (t < 256) {  // per-bucket sums
    int s0 = bstart[t], s1 = s0 + cnt[t];
    float ap = 0.f, an = 0.f;
    for (int q = s0; q < s1; ++q) { ap += Sp[q]; an += Sn[q]; }
    bsP[t] = ap; bsN[t] = an;
  }
  __syncthreads();
  if (wv == 0) {  // bucket-level exclusive prefix(P) / suffix(N)
    int b4 = lane * 4;
    float p0 = bsP[b4], p1 = bsP[b4 + 1], p2 = bsP[b4 + 2], p3 = bsP[b4 + 3];
    float n0 = bsN[b4], n1 = bsN[b4 + 1], n2 = bsN[b4 + 2], n3 = bsN[b4 + 3];
    float tp = p0 + p1 + p2 + p3, tn = n0 + n1 + n2 + n3;
    float ip = tp, in_ = tn;
#pragma unroll
    for (int d = 1; d < 64; d <<= 1) {
      float yp = __shfl_up(ip, d);
      float yn = __shfl_up(in_, d);
      if (lane >= d) { ip += yp; in_ += yn; }
    }
    float totn = __shfl(in_, 63);
    float runp = ip - tp;
    float runn = in_ - tn;
    Pbel[b4] = runp; Nab[b4] = totn - runn - n0; runp += p0; runn += n0;
    Pbel[b4 + 1] = runp; Nab[b4 + 1] = totn - runn - n1; runp += p1; runn += n1;
    Pbel[b4 + 2] = runp; Nab[b4 + 2] = totn - runn - n2; runp += p2; runn += n2;
    Pbel[b4 + 3] = runp; Nab[b4 + 3] = totn - runn - n3;
  }
  __syncthreads();
#pragma unroll
  for (int r = 0; r < 2; ++r) {
    int s = t + r * 1024;
    int meta = Smeta[s];
    int b = meta >> 16;
    int idx = meta & 0xFFFF;
    float p = Sp[s], n = Sn[s];
    float acc = n * Pbel[b] + p * Nab[b];
    int q0 = bstart[b], q1 = q0 + cnt[b];
    for (int q = q0; q < q1; ++q) acc += fminf(p * Sn[q], n * Sp[q]);
    atomicAdd(&out[idx], acc * wff);  // fused final: feats contribution
  }
}

extern "C" void kernel_launch(void* const* d_in, const int* in_sizes, int n_in,
                              void* d_out, int out_size, void* d_ws, size_t ws_size,
                              hipStream_t stream) {
  const float* x  = (const float*)d_in[0];
  const float* W1 = (const float*)d_in[1];
  const float* b1 = (const float*)d_in[2];
  const float* W2 = (const float*)d_in[3];
  const float* b2 = (const float*)d_in[4];
  const float* T  = (const float*)d_in[5];
  const float* Wf = (const float*)d_in[6];
  const float* bf = (const float*)d_in[7];
  float* out = (float*)d_out;

  char* w = (char*)d_ws;
  auto alloc = [&](size_t b) { char* p = w; w += (b + 255) & ~(size_t)255; return p; };
  __hip_bfloat16* W1t = (__hip_bfloat16*)alloc(512L * 3072 * 2);   // 3 MB
  __hip_bfloat16* W2t = (__hip_bfloat16*)alloc(256L * 512 * 2);
  __hip_bfloat16* Tt  = (__hip_bfloat16*)alloc(128L * 256 * 2);
  float*          h2f = (float*)alloc(2048L * 256 * 4);            // 2 MB
  __hip_bfloat16* h2b = (__hip_bfloat16*)alloc(2048L * 256 * 2);   // 1 MB
  float*          P1  = (float*)alloc(3L * 2048 * 512 * 4);        // 12 MB
  float*          P3  = (float*)alloc(4L * 2048 * 128 * 4);        // 4 MB

  // 1) weight transposes
  k_prep<<<1696, 256, 0, stream>>>(W1, W1t, W2, W2t, T, Tt);
  // 2) G1: x(fp32) @ W1t, convert-on-stage, split-K=3
  k_gemm1<<<dim3(32, 8, 3), 256, 0, stream>>>(x, W1t, P1);
  // 3) G2: (comb1 fused on stage) @ W2t, full-K, fused b2+leaky -> h2b+h2f
  k_gemm2<<<dim3(32, 4), 256, 0, stream>>>(P1, b1, W2t, b2, h2b, h2f);
  // 4) G3: h2b @ Tt, split-K=4, transposed partials; zeroes out[]
  k_gemm3<<<dim3(32, 2, 4), 256, 0, stream>>>(h2b, Tt, P3, out);
  // 5) bucketed features + fused final dot (atomicAdd)
  k_bucketfinal<<<102, 1024, 0, stream>>>(P3, h2f, Wf, bf, out);
}